// Round 7
// baseline (149.949 us; speedup 1.0000x reference)
//
#include <hip/hip_runtime.h>
#include <math.h>

// ---------------------------------------------------------------------------
// GCN: 3x GCNConv (linear) -> mean pool -> linear -> sigmoid.
// Linear-collapse identity (absmax 0.0 through R6):
//   h3 @ lin_w = A(A(A(X u) + s2) + s1) + s0,  u = W1W2W3 lin_w.
// R6 lesson: scatter write-amp returned (WRITE 67MB for 12.8MB) because
// BSZ=128 made per-(bucket,block) runs 64B. R7: decouple scatter-run length
// from gather balance: BSZ=256 (nbuck=391), NB_SCAT=128 -> runs = 256B
// (4 lines, amp ~1.25x); gather kernels use 512-thread blocks (391 x 8
// waves = same TLP as R6's 782 x 4).
// ---------------------------------------------------------------------------

#define SHIFT      8
#define BSZ        256         // nodes per bucket = 1<<SHIFT
#define NB_SCAT    128         // blocks for hist/scatter phases
#define B_SCAT     256         // threads for hist/scatter
#define B_GATH     512         // threads for bucket (gather) kernels
#define ROWMASK    0x1FFFFu    // 17 bits for row id (n < 131072)
#define PSLOTS     64          // LDS pool slots per pass-3 block

// ---- K1: histogram of col>>SHIFT (M[j][bin]) + coeffs + sums/cnt zero ----
__global__ void hist_kernel(const int* __restrict__ col, int E, int tile, int nbuck,
                            unsigned* __restrict__ M,
                            const float* __restrict__ W1, const float* __restrict__ b1,
                            const float* __restrict__ W2, const float* __restrict__ b2,
                            const float* __restrict__ W3, const float* __restrict__ b3,
                            const float* __restrict__ lin_w, const float* __restrict__ lin_b,
                            float* __restrict__ coeff,
                            float* __restrict__ sums, float* __restrict__ cnt, int ngraphs) {
    extern __shared__ unsigned h[];
    __shared__ float w3l[16], w2l[16];
    int t = threadIdx.x;
    for (int i = t; i < nbuck; i += blockDim.x) h[i] = 0;
    if (blockIdx.x == 0) {
        for (int i = t; i < ngraphs; i += blockDim.x) { sums[i] = 0.f; cnt[i] = 0.f; }
        if (t < 16) {
            float s = 0.f;
            for (int j = 0; j < 16; ++j) s += W3[t * 16 + j] * lin_w[j];
            w3l[t] = s;
        }
    }
    __syncthreads();
    if (blockIdx.x == 0 && t < 16) {
        float s = 0.f;
        for (int j = 0; j < 16; ++j) s += W2[t * 16 + j] * w3l[j];
        w2l[t] = s;
    }
    __syncthreads();
    if (blockIdx.x == 0) {
        if (t < 4) {
            float s = 0.f;
            for (int j = 0; j < 16; ++j) s += W1[t * 16 + j] * w2l[j];
            coeff[t] = s;
        } else if (t == 4) {
            float s = 0.f;
            for (int j = 0; j < 16; ++j) s += b1[j] * w2l[j];
            coeff[4] = s;
        } else if (t == 5) {
            float s = 0.f;
            for (int j = 0; j < 16; ++j) s += b2[j] * w3l[j];
            coeff[5] = s;
        } else if (t == 6) {
            float s = 0.f;
            for (int j = 0; j < 16; ++j) s += b3[j] * lin_w[j];
            coeff[6] = s;
        } else if (t == 7) {
            coeff[7] = lin_b[0];
        }
    }
    // histogram
    int b = blockIdx.x;
    int s = b * tile, e = min(s + tile, E);          // s multiple of 4
    if (s < e) {
        int nq = (e - s) >> 2;
        const int4* c4 = (const int4*)(col + s);
        for (int q = t; q < nq; q += blockDim.x) {
            int4 c = c4[q];
            atomicAdd(&h[((unsigned)c.x) >> SHIFT], 1u);
            atomicAdd(&h[((unsigned)c.y) >> SHIFT], 1u);
            atomicAdd(&h[((unsigned)c.z) >> SHIFT], 1u);
            atomicAdd(&h[((unsigned)c.w) >> SHIFT], 1u);
        }
        for (int k = s + (nq << 2) + t; k < e; k += blockDim.x)
            atomicAdd(&h[((unsigned)col[k]) >> SHIFT], 1u);
    }
    __syncthreads();
    for (int i = t; i < nbuck; i += blockDim.x)
        M[(size_t)b * nbuck + i] = h[i];
}

// ---- K2: per-bin exclusive scan over the NB_SCAT block counts ----
__global__ void scanA_kernel(unsigned* __restrict__ M, unsigned* __restrict__ binTotal,
                             int nbuck) {
    __shared__ unsigned sc[NB_SCAT];
    int b = blockIdx.x;
    int t = threadIdx.x;
    unsigned v = M[(size_t)t * nbuck + b];
    sc[t] = v;
    __syncthreads();
    for (int off = 1; off < NB_SCAT; off <<= 1) {
        unsigned u = (t >= off) ? sc[t - off] : 0u;
        __syncthreads();
        sc[t] += u;
        __syncthreads();
    }
    M[(size_t)t * nbuck + b] = sc[t] - v;     // exclusive within bin
    if (t == NB_SCAT - 1) binTotal[b] = sc[t];
}

// ---- K3: scatter into buckets; each block scans binTotal in LDS ----
// pack: row(17b) | col_low(8b)<<17
__global__ void scatter_kernel(const int* __restrict__ row, const int* __restrict__ col,
                               int E, int tile, int nbuck,
                               const unsigned* __restrict__ M,
                               const unsigned* __restrict__ binTotal,
                               unsigned* __restrict__ bstart,
                               unsigned* __restrict__ out) {
    extern __shared__ unsigned lds[];        // bb[nbuck] | base[nbuck] | tsum[B_SCAT]
    unsigned* bb   = lds;
    unsigned* base = lds + nbuck;
    unsigned* tsum = lds + 2 * nbuck;
    int t = threadIdx.x;
    const int C = (2048 + B_SCAT - 1) / B_SCAT;   // elems/thread covering nbuck<=2048
    unsigned lv[C];
    unsigned ls = 0;
    for (int k = 0; k < C; ++k) {
        int i = t * C + k;
        unsigned x = (i < nbuck) ? binTotal[i] : 0u;
        lv[k] = ls; ls += x;
    }
    tsum[t] = ls;
    __syncthreads();
    for (int off = 1; off < B_SCAT; off <<= 1) {
        unsigned u = (t >= off) ? tsum[t - off] : 0u;
        __syncthreads();
        tsum[t] += u;
        __syncthreads();
    }
    unsigned ex = (t == 0) ? 0u : tsum[t - 1];
    for (int k = 0; k < C; ++k) {
        int i = t * C + k;
        if (i < nbuck) bb[i] = ex + lv[k];
    }
    __syncthreads();
    int j = blockIdx.x;
    for (int i = t; i < nbuck; i += blockDim.x)
        base[i] = bb[i] + M[(size_t)j * nbuck + i];
    if (j == 0) {
        for (int i = t; i < nbuck; i += blockDim.x) bstart[i] = bb[i];
        if (t == 0) bstart[nbuck] = (unsigned)E;
    }
    __syncthreads();
    int s = j * tile, e = min(s + tile, E);
    if (s < e) {
        int nq = (e - s) >> 2;
        const int4* r4 = (const int4*)(row + s);
        const int4* c4 = (const int4*)(col + s);
        for (int q = t; q < nq; q += blockDim.x) {
            int4 r = r4[q];
            int4 c = c4[q];
            unsigned p0 = atomicAdd(&base[((unsigned)c.x) >> SHIFT], 1u);
            unsigned p1 = atomicAdd(&base[((unsigned)c.y) >> SHIFT], 1u);
            unsigned p2 = atomicAdd(&base[((unsigned)c.z) >> SHIFT], 1u);
            unsigned p3 = atomicAdd(&base[((unsigned)c.w) >> SHIFT], 1u);
            out[p0] = (unsigned)r.x | (((unsigned)c.x & (BSZ - 1)) << 17);
            out[p1] = (unsigned)r.y | (((unsigned)c.y & (BSZ - 1)) << 17);
            out[p2] = (unsigned)r.z | (((unsigned)c.z & (BSZ - 1)) << 17);
            out[p3] = (unsigned)r.w | (((unsigned)c.w & (BSZ - 1)) << 17);
        }
        for (int k = s + (nq << 2) + t; k < e; k += blockDim.x) {
            unsigned c = (unsigned)col[k];
            unsigned pos = atomicAdd(&base[c >> SHIFT], 1u);
            out[pos] = (unsigned)row[k] | ((c & (BSZ - 1)) << 17);
        }
    }
}

// ---- K4: degree count + node0 epilogue (dinv, g0 = dinv * x.u) ----
__global__ void degnode0_kernel(const unsigned* __restrict__ buck,
                                const unsigned* __restrict__ bstart,
                                const float* __restrict__ x, const float* __restrict__ coeff,
                                float* __restrict__ dinv, float* __restrict__ g, int n) {
    __shared__ float acc[BSZ];
    int b = blockIdx.x;
    if (threadIdx.x < BSZ) acc[threadIdx.x] = 0.f;
    __syncthreads();
    unsigned s = bstart[b], e = bstart[b + 1];
    unsigned sa = (s + 3u) & ~3u;
    if (sa > e) sa = e;
    if (s + threadIdx.x < sa)
        atomicAdd(&acc[buck[s + threadIdx.x] >> 17], 1.0f);
    unsigned nq = (e - sa) >> 2;
    const uint4* bq = (const uint4*)(buck + sa);
    for (unsigned q = threadIdx.x; q < nq; q += blockDim.x) {
        uint4 w = bq[q];
        atomicAdd(&acc[w.x >> 17], 1.0f);
        atomicAdd(&acc[w.y >> 17], 1.0f);
        atomicAdd(&acc[w.z >> 17], 1.0f);
        atomicAdd(&acc[w.w >> 17], 1.0f);
    }
    for (unsigned k = sa + (nq << 2) + threadIdx.x; k < e; k += blockDim.x)
        atomicAdd(&acc[buck[k] >> 17], 1.0f);
    __syncthreads();
    int node = b * BSZ + threadIdx.x;
    if (threadIdx.x < BSZ && node < n) {
        float d = rsqrtf(acc[threadIdx.x] + 1.0f);
        dinv[node] = d;
        float4 xv = ((const float4*)x)[node];
        float t0 = xv.x * coeff[0] + xv.y * coeff[1] + xv.z * coeff[2] + xv.w * coeff[3];
        g[node] = d * t0;
    }
}

// ---- K5/K6: gather pass with fused node epilogue ----
__global__ void gather_kernel(const unsigned* __restrict__ buck,
                              const unsigned* __restrict__ bstart,
                              const float* __restrict__ dinv, const float* __restrict__ gin,
                              float* __restrict__ gout, const float* __restrict__ coeff,
                              int sidx, int n) {
    __shared__ float acc[BSZ];
    int b = blockIdx.x;
    if (threadIdx.x < BSZ) acc[threadIdx.x] = 0.f;
    __syncthreads();
    unsigned s = bstart[b], e = bstart[b + 1];
    unsigned sa = (s + 3u) & ~3u;
    if (sa > e) sa = e;
    if (s + threadIdx.x < sa) {
        unsigned w = buck[s + threadIdx.x];
        atomicAdd(&acc[w >> 17], gin[w & ROWMASK]);
    }
    unsigned nq = (e - sa) >> 2;
    const uint4* bq = (const uint4*)(buck + sa);
    for (unsigned q = threadIdx.x; q < nq; q += blockDim.x) {
        uint4 w = bq[q];
        float a0 = gin[w.x & ROWMASK];
        float a1 = gin[w.y & ROWMASK];
        float a2 = gin[w.z & ROWMASK];
        float a3 = gin[w.w & ROWMASK];
        atomicAdd(&acc[w.x >> 17], a0);
        atomicAdd(&acc[w.y >> 17], a1);
        atomicAdd(&acc[w.z >> 17], a2);
        atomicAdd(&acc[w.w >> 17], a3);
    }
    for (unsigned k = sa + (nq << 2) + threadIdx.x; k < e; k += blockDim.x) {
        unsigned w = buck[k];
        atomicAdd(&acc[w >> 17], gin[w & ROWMASK]);
    }
    __syncthreads();
    int node = b * BSZ + threadIdx.x;
    if (threadIdx.x < BSZ && node < n) {
        float d = dinv[node];
        float t = d * (acc[threadIdx.x] + gin[node]) + coeff[sidx];
        gout[node] = d * t;
    }
}

// ---- K7: pass 3 gather + fused segmented mean-pool (batch sorted) ----
__global__ void gatherpool_kernel(const unsigned* __restrict__ buck,
                                  const unsigned* __restrict__ bstart,
                                  const float* __restrict__ dinv, const float* __restrict__ gin,
                                  const float* __restrict__ coeff, const int* __restrict__ batch,
                                  float* __restrict__ sums, float* __restrict__ cnt, int n) {
    __shared__ float acc[BSZ];
    __shared__ float ls[PSLOTS], lc[PSLOTS];
    __shared__ int bF;
    int b = blockIdx.x;
    if (threadIdx.x < BSZ) acc[threadIdx.x] = 0.f;
    for (int i = threadIdx.x; i < PSLOTS; i += blockDim.x) { ls[i] = 0.f; lc[i] = 0.f; }
    if (threadIdx.x == 0) bF = batch[min(b * BSZ, n - 1)];
    __syncthreads();
    unsigned s = bstart[b], e = bstart[b + 1];
    unsigned sa = (s + 3u) & ~3u;
    if (sa > e) sa = e;
    if (s + threadIdx.x < sa) {
        unsigned w = buck[s + threadIdx.x];
        atomicAdd(&acc[w >> 17], gin[w & ROWMASK]);
    }
    unsigned nq = (e - sa) >> 2;
    const uint4* bq = (const uint4*)(buck + sa);
    for (unsigned q = threadIdx.x; q < nq; q += blockDim.x) {
        uint4 w = bq[q];
        float a0 = gin[w.x & ROWMASK];
        float a1 = gin[w.y & ROWMASK];
        float a2 = gin[w.z & ROWMASK];
        float a3 = gin[w.w & ROWMASK];
        atomicAdd(&acc[w.x >> 17], a0);
        atomicAdd(&acc[w.y >> 17], a1);
        atomicAdd(&acc[w.z >> 17], a2);
        atomicAdd(&acc[w.w >> 17], a3);
    }
    for (unsigned k = sa + (nq << 2) + threadIdx.x; k < e; k += blockDim.x) {
        unsigned w = buck[k];
        atomicAdd(&acc[w >> 17], gin[w & ROWMASK]);
    }
    __syncthreads();
    int node = b * BSZ + threadIdx.x;
    if (threadIdx.x < BSZ && node < n) {
        float d = dinv[node];
        float t3 = d * (acc[threadIdx.x] + gin[node]) + coeff[6];
        int rb = batch[node] - bF;               // batch sorted -> rb >= 0
        if (rb < PSLOTS) {
            atomicAdd(&ls[rb], t3);
            atomicAdd(&lc[rb], 1.0f);
        } else {
            atomicAdd(&sums[bF + rb], t3);
            atomicAdd(&cnt[bF + rb], 1.0f);
        }
    }
    __syncthreads();
    for (int i = threadIdx.x; i < PSLOTS; i += blockDim.x) {
        if (lc[i] != 0.f) {
            atomicAdd(&sums[bF + i], ls[i]);
            atomicAdd(&cnt[bF + i], lc[i]);
        }
    }
}

// ---- K8: mean + linear bias + sigmoid ----
__global__ void final_kernel(const float* __restrict__ sums, const float* __restrict__ cnt,
                             const float* __restrict__ coeff, float* __restrict__ out,
                             int ngraphs) {
    int i = blockIdx.x * blockDim.x + threadIdx.x;
    if (i < ngraphs) {
        float m = sums[i] / fmaxf(cnt[i], 1.0f) + coeff[7];
        out[i] = 1.0f / (1.0f + expf(-m));
    }
}

// ======================= fallback (R1 atomic path) =========================
__global__ void fb_coeffs_kernel(const float* __restrict__ W1, const float* __restrict__ b1,
                                 const float* __restrict__ W2, const float* __restrict__ b2,
                                 const float* __restrict__ W3, const float* __restrict__ b3,
                                 const float* __restrict__ lin_w, const float* __restrict__ lin_b,
                                 float* __restrict__ coeff,
                                 float* __restrict__ sums, float* __restrict__ cnt, int ngraphs) {
    for (int i = threadIdx.x; i < ngraphs; i += blockDim.x) { sums[i] = 0.f; cnt[i] = 0.f; }
    if (threadIdx.x == 0) {
        float w3l[16], w2l[16];
        for (int i = 0; i < 16; ++i) {
            float s = 0.f;
            for (int j = 0; j < 16; ++j) s += W3[i * 16 + j] * lin_w[j];
            w3l[i] = s;
        }
        for (int i = 0; i < 16; ++i) {
            float s = 0.f;
            for (int j = 0; j < 16; ++j) s += W2[i * 16 + j] * w3l[j];
            w2l[i] = s;
        }
        for (int i = 0; i < 4; ++i) {
            float s = 0.f;
            for (int j = 0; j < 16; ++j) s += W1[i * 16 + j] * w2l[j];
            coeff[i] = s;
        }
        float s2 = 0.f, s1 = 0.f, s0 = 0.f;
        for (int j = 0; j < 16; ++j) {
            s2 += b1[j] * w2l[j];
            s1 += b2[j] * w3l[j];
            s0 += b3[j] * lin_w[j];
        }
        coeff[4] = s2; coeff[5] = s1; coeff[6] = s0; coeff[7] = lin_b[0];
    }
}
__global__ void fb_init_kernel(float* __restrict__ deg, int n) {
    int i = blockIdx.x * blockDim.x + threadIdx.x;
    int stride = gridDim.x * blockDim.x;
    for (int k = i; k < n; k += stride) deg[k] = 1.0f;
}
__global__ void fb_deg_kernel(const int* __restrict__ col, float* __restrict__ deg, int E) {
    int i = blockIdx.x * blockDim.x + threadIdx.x;
    int stride = gridDim.x * blockDim.x;
    for (int k = i; k < E; k += stride) atomicAdd(&deg[col[k]], 1.0f);
}
__global__ void fb_node0_kernel(const float* __restrict__ x, const float* __restrict__ coeff,
                                float* __restrict__ deg_dinv, float* __restrict__ g,
                                float* __restrict__ acc, int n) {
    int i = blockIdx.x * blockDim.x + threadIdx.x;
    int stride = gridDim.x * blockDim.x;
    for (int k = i; k < n; k += stride) {
        float d = rsqrtf(deg_dinv[k]);
        deg_dinv[k] = d;
        float4 xv = ((const float4*)x)[k];
        float t0 = xv.x * coeff[0] + xv.y * coeff[1] + xv.z * coeff[2] + xv.w * coeff[3];
        g[k] = d * t0;
        acc[k] = 0.f;
    }
}
__global__ void fb_edge_kernel(const int* __restrict__ ei, const float* __restrict__ g,
                               float* __restrict__ acc, int E) {
    int i = blockIdx.x * blockDim.x + threadIdx.x;
    int stride = gridDim.x * blockDim.x;
    for (int k = i; k < E; k += stride) atomicAdd(&acc[ei[E + k]], g[ei[k]]);
}
__global__ void fb_node_kernel(const float* __restrict__ dinv, float* __restrict__ g,
                               float* __restrict__ acc, const float* __restrict__ coeff,
                               int sidx, int n) {
    int i = blockIdx.x * blockDim.x + threadIdx.x;
    int stride = gridDim.x * blockDim.x;
    for (int k = i; k < n; k += stride) {
        float d = dinv[k];
        float t = d * (acc[k] + g[k]) + coeff[sidx];
        g[k] = d * t;
        acc[k] = 0.f;
    }
}
__global__ void fb_pool_kernel(const float* __restrict__ dinv, const float* __restrict__ g,
                               const float* __restrict__ acc, const float* __restrict__ coeff,
                               const int* __restrict__ batch, float* __restrict__ sums,
                               float* __restrict__ cnt, int n) {
    int i = blockIdx.x * blockDim.x + threadIdx.x;
    int stride = gridDim.x * blockDim.x;
    for (int k = i; k < n; k += stride) {
        float d = dinv[k];
        float t3 = d * (acc[k] + g[k]) + coeff[6];
        int b = batch[k];
        atomicAdd(&sums[b], t3);
        atomicAdd(&cnt[b], 1.0f);
    }
}
// ===========================================================================

extern "C" void kernel_launch(void* const* d_in, const int* in_sizes, int n_in,
                              void* d_out, int out_size, void* d_ws, size_t ws_size,
                              hipStream_t stream) {
    const float* x     = (const float*)d_in[0];
    const int*   ei    = (const int*)d_in[1];
    const int*   batch = (const int*)d_in[2];
    const float* W1    = (const float*)d_in[3];
    const float* b1    = (const float*)d_in[4];
    const float* W2    = (const float*)d_in[5];
    const float* b2    = (const float*)d_in[6];
    const float* W3    = (const float*)d_in[7];
    const float* b3    = (const float*)d_in[8];
    const float* lin_w = (const float*)d_in[9];
    const float* lin_b = (const float*)d_in[10];

    const int n       = in_sizes[0] / 4;   // 100000
    const int E       = in_sizes[1] / 2;   // 3200000
    const int ngraphs = out_size;          // 1000

    const int nbuck = (n + BSZ - 1) / BSZ; // 391
    const int B = 256;

    size_t npad  = ((size_t)n + 255) & ~(size_t)255;
    size_t gpad  = ((size_t)ngraphs + 255) & ~(size_t)255;
    size_t nbpad = ((size_t)nbuck + 1 + 255) & ~(size_t)255;
    size_t mlen  = (size_t)NB_SCAT * nbuck;

    size_t need = (256 + mlen + 2 * nbpad + (size_t)E + 3 * npad + 2 * gpad) * 4;

    float* ws    = (float*)d_ws;
    float* coeff = ws;                                    // 256
    unsigned* M        = (unsigned*)(coeff + 256);        // mlen
    unsigned* binTotal = M + mlen;                        // nbpad
    unsigned* bstart   = binTotal + nbpad;                // nbpad
    unsigned* buck     = bstart + nbpad;                  // E (16B aligned)
    float* dinv  = (float*)(buck + E);                    // npad
    float* gA    = dinv + npad;                           // npad
    float* gB    = gA + npad;                             // npad
    float* sums  = gB + npad;                             // gpad
    float* cnt   = sums + gpad;                           // gpad

    bool mainok = (n < (1 << 17)) && nbuck >= 1 && nbuck <= 2048 && ws_size >= need;

    if (!mainok) {
        // -------- fallback: R1 atomic path --------
        float* fcoeff = ws;
        float* deg = fcoeff + 256;
        float* g   = deg + npad;
        float* acc = g + npad;
        float* fsums = acc + npad;
        float* fcnt  = fsums + gpad;
        int nodeBlocks = (n + B - 1) / B;
        int edgeBlocks = (E + B - 1) / B;
        fb_coeffs_kernel<<<1, 64, 0, stream>>>(W1, b1, W2, b2, W3, b3, lin_w, lin_b, fcoeff,
                                               fsums, fcnt, ngraphs);
        fb_init_kernel<<<nodeBlocks, B, 0, stream>>>(deg, n);
        fb_deg_kernel<<<edgeBlocks, B, 0, stream>>>(ei + E, deg, E);
        fb_node0_kernel<<<nodeBlocks, B, 0, stream>>>(x, fcoeff, deg, g, acc, n);
        fb_edge_kernel<<<edgeBlocks, B, 0, stream>>>(ei, g, acc, E);
        fb_node_kernel<<<nodeBlocks, B, 0, stream>>>(deg, g, acc, fcoeff, 4, n);
        fb_edge_kernel<<<edgeBlocks, B, 0, stream>>>(ei, g, acc, E);
        fb_node_kernel<<<nodeBlocks, B, 0, stream>>>(deg, g, acc, fcoeff, 5, n);
        fb_edge_kernel<<<edgeBlocks, B, 0, stream>>>(ei, g, acc, E);
        fb_pool_kernel<<<nodeBlocks, B, 0, stream>>>(deg, g, acc, fcoeff, batch, fsums, fcnt, n);
        final_kernel<<<(ngraphs + B - 1) / B, B, 0, stream>>>(fsums, fcnt, fcoeff, (float*)d_out, ngraphs);
        return;
    }

    int tile = (((E + NB_SCAT - 1) / NB_SCAT) + 3) & ~3;   // multiple of 4
    size_t ldsHist = (size_t)nbuck * sizeof(unsigned);
    size_t ldsScat = (size_t)(2 * nbuck + B_SCAT) * sizeof(unsigned);

    hist_kernel<<<NB_SCAT, B_SCAT, ldsHist, stream>>>(ei + E, E, tile, nbuck, M,
                                                      W1, b1, W2, b2, W3, b3, lin_w, lin_b,
                                                      coeff, sums, cnt, ngraphs);
    scanA_kernel<<<nbuck, NB_SCAT, 0, stream>>>(M, binTotal, nbuck);
    scatter_kernel<<<NB_SCAT, B_SCAT, ldsScat, stream>>>(ei, ei + E, E, tile, nbuck, M,
                                                         binTotal, bstart, buck);

    degnode0_kernel<<<nbuck, B_GATH, 0, stream>>>(buck, bstart, x, coeff, dinv, gA, n);
    gather_kernel<<<nbuck, B_GATH, 0, stream>>>(buck, bstart, dinv, gA, gB, coeff, 4, n);
    gather_kernel<<<nbuck, B_GATH, 0, stream>>>(buck, bstart, dinv, gB, gA, coeff, 5, n);
    gatherpool_kernel<<<nbuck, B_GATH, 0, stream>>>(buck, bstart, dinv, gA, coeff, batch,
                                                    sums, cnt, n);

    final_kernel<<<(ngraphs + B - 1) / B, B, 0, stream>>>(sums, cnt, coeff, (float*)d_out, ngraphs);
}

// Round 8
// 146.612 us; speedup vs baseline: 1.0228x; 1.0228x over previous
//
#include <hip/hip_runtime.h>
#include <math.h>

// ---------------------------------------------------------------------------
// GCN: 3x GCNConv (linear) -> mean pool -> linear -> sigmoid.
// Linear-collapse identity (absmax 0.0 through R7):
//   h3 @ lin_w = A(A(A(X u) + s2) + s1) + s0,  u = W1W2W3 lin_w.
// R7 lesson: scatter WRITE_SIZE dropped to ~ideal but time stayed 50us ->
// bound by write TRANSACTIONS (64 lanes hit 64 lines), not bytes.
// R8: block-local LDS counting sort; flush writes are per-wave coalesced
// (consecutive addresses within each bucket run). LDS ~56KB/block.
// ---------------------------------------------------------------------------

#define SHIFT      8
#define BSZ        256         // nodes per bucket = 1<<SHIFT
#define NB_SCAT    256         // blocks for hist/scatter phases
#define B_SCAT     256         // threads for hist/scatter
#define B_GATH     512         // threads for bucket (gather) kernels
#define ROWMASK    0x1FFFFu    // 17 bits for row id (n < 131072)
#define PSLOTS     64          // LDS pool slots per pass-3 block
#define MAXNB      2048        // nbuck guard (scan chunking)

// ---- K1: histogram of col>>SHIFT (M[j][bin]) + coeffs + sums/cnt zero ----
__global__ void hist_kernel(const int* __restrict__ col, int E, int tile, int nbuck,
                            unsigned* __restrict__ M,
                            const float* __restrict__ W1, const float* __restrict__ b1,
                            const float* __restrict__ W2, const float* __restrict__ b2,
                            const float* __restrict__ W3, const float* __restrict__ b3,
                            const float* __restrict__ lin_w, const float* __restrict__ lin_b,
                            float* __restrict__ coeff,
                            float* __restrict__ sums, float* __restrict__ cnt, int ngraphs) {
    extern __shared__ unsigned h[];
    __shared__ float w3l[16], w2l[16];
    int t = threadIdx.x;
    for (int i = t; i < nbuck; i += blockDim.x) h[i] = 0;
    if (blockIdx.x == 0) {
        for (int i = t; i < ngraphs; i += blockDim.x) { sums[i] = 0.f; cnt[i] = 0.f; }
        if (t < 16) {
            float s = 0.f;
            for (int j = 0; j < 16; ++j) s += W3[t * 16 + j] * lin_w[j];
            w3l[t] = s;
        }
    }
    __syncthreads();
    if (blockIdx.x == 0 && t < 16) {
        float s = 0.f;
        for (int j = 0; j < 16; ++j) s += W2[t * 16 + j] * w3l[j];
        w2l[t] = s;
    }
    __syncthreads();
    if (blockIdx.x == 0) {
        if (t < 4) {
            float s = 0.f;
            for (int j = 0; j < 16; ++j) s += W1[t * 16 + j] * w2l[j];
            coeff[t] = s;
        } else if (t == 4) {
            float s = 0.f;
            for (int j = 0; j < 16; ++j) s += b1[j] * w2l[j];
            coeff[4] = s;
        } else if (t == 5) {
            float s = 0.f;
            for (int j = 0; j < 16; ++j) s += b2[j] * w3l[j];
            coeff[5] = s;
        } else if (t == 6) {
            float s = 0.f;
            for (int j = 0; j < 16; ++j) s += b3[j] * lin_w[j];
            coeff[6] = s;
        } else if (t == 7) {
            coeff[7] = lin_b[0];
        }
    }
    // histogram
    int b = blockIdx.x;
    int s = b * tile, e = min(s + tile, E);          // s multiple of 4
    if (s < e) {
        int nq = (e - s) >> 2;
        const int4* c4 = (const int4*)(col + s);
        for (int q = t; q < nq; q += blockDim.x) {
            int4 c = c4[q];
            atomicAdd(&h[((unsigned)c.x) >> SHIFT], 1u);
            atomicAdd(&h[((unsigned)c.y) >> SHIFT], 1u);
            atomicAdd(&h[((unsigned)c.z) >> SHIFT], 1u);
            atomicAdd(&h[((unsigned)c.w) >> SHIFT], 1u);
        }
        for (int k = s + (nq << 2) + t; k < e; k += blockDim.x)
            atomicAdd(&h[((unsigned)col[k]) >> SHIFT], 1u);
    }
    __syncthreads();
    for (int i = t; i < nbuck; i += blockDim.x)
        M[(size_t)b * nbuck + i] = h[i];
}

// ---- K2: per-bin exclusive scan over the NB_SCAT block counts ----
__global__ void scanA_kernel(unsigned* __restrict__ M, unsigned* __restrict__ binTotal,
                             int nbuck) {
    __shared__ unsigned sc[NB_SCAT];
    int b = blockIdx.x;
    int t = threadIdx.x;
    unsigned v = M[(size_t)t * nbuck + b];
    sc[t] = v;
    __syncthreads();
    for (int off = 1; off < NB_SCAT; off <<= 1) {
        unsigned u = (t >= off) ? sc[t - off] : 0u;
        __syncthreads();
        sc[t] += u;
        __syncthreads();
    }
    M[(size_t)t * nbuck + b] = sc[t] - v;     // exclusive within bin
    if (t == NB_SCAT - 1) binTotal[b] = sc[t];
}

// ---- K3: scatter via block-local LDS counting sort; coalesced flush ----
// pack: row(17b) | col_low(8b)<<17
__global__ void scatter_kernel(const int* __restrict__ row, const int* __restrict__ col,
                               int E, int tile, int nbuck,
                               const unsigned* __restrict__ M,
                               const unsigned* __restrict__ binTotal,
                               unsigned* __restrict__ bstart,
                               unsigned* __restrict__ out) {
    extern __shared__ unsigned lds[];
    unsigned* h     = lds;                   // nbuck  local counts
    unsigned* lofs  = lds + nbuck;           // nbuck  local exclusive offsets
    unsigned* lcur  = lds + 2 * nbuck;       // nbuck  placement cursors
    unsigned* gbase = lds + 3 * nbuck;       // nbuck  global run starts (this block)
    unsigned* tsum  = lds + 4 * nbuck;       // B_SCAT scan workspace
    unsigned* stage = lds + 4 * nbuck + B_SCAT; // tile  staged packed words
    int t = threadIdx.x, j = blockIdx.x;
    for (int i = t; i < nbuck; i += blockDim.x) h[i] = 0;
    __syncthreads();
    int s = j * tile, e = min(s + tile, E);
    // 1. local hist
    if (s < e) {
        int nq = (e - s) >> 2;
        const int4* c4 = (const int4*)(col + s);
        for (int q = t; q < nq; q += blockDim.x) {
            int4 c = c4[q];
            atomicAdd(&h[((unsigned)c.x) >> SHIFT], 1u);
            atomicAdd(&h[((unsigned)c.y) >> SHIFT], 1u);
            atomicAdd(&h[((unsigned)c.z) >> SHIFT], 1u);
            atomicAdd(&h[((unsigned)c.w) >> SHIFT], 1u);
        }
        for (int k = s + (nq << 2) + t; k < e; k += blockDim.x)
            atomicAdd(&h[((unsigned)col[k]) >> SHIFT], 1u);
    }
    __syncthreads();
    const int C = MAXNB / B_SCAT;            // 8 elems/thread
    unsigned lv[C];
    // 2. scan h -> lofs/lcur (exclusive)
    {
        unsigned run = 0;
        for (int k = 0; k < C; ++k) {
            int i = t * C + k;
            unsigned x = (i < nbuck) ? h[i] : 0u;
            lv[k] = run; run += x;
        }
        tsum[t] = run;
        __syncthreads();
        for (int off = 1; off < B_SCAT; off <<= 1) {
            unsigned u = (t >= off) ? tsum[t - off] : 0u;
            __syncthreads();
            tsum[t] += u;
            __syncthreads();
        }
        unsigned ex = (t == 0) ? 0u : tsum[t - 1];
        for (int k = 0; k < C; ++k) {
            int i = t * C + k;
            if (i < nbuck) { lofs[i] = ex + lv[k]; lcur[i] = ex + lv[k]; }
        }
    }
    __syncthreads();
    // 3. gbase[i] = (exclusive scan of binTotal)[i] + M[j][i]; block 0 stores bstart
    {
        unsigned run = 0;
        for (int k = 0; k < C; ++k) {
            int i = t * C + k;
            unsigned x = (i < nbuck) ? binTotal[i] : 0u;
            lv[k] = run; run += x;
        }
        tsum[t] = run;
        __syncthreads();
        for (int off = 1; off < B_SCAT; off <<= 1) {
            unsigned u = (t >= off) ? tsum[t - off] : 0u;
            __syncthreads();
            tsum[t] += u;
            __syncthreads();
        }
        unsigned ex = (t == 0) ? 0u : tsum[t - 1];
        for (int k = 0; k < C; ++k) {
            int i = t * C + k;
            if (i < nbuck) {
                unsigned bb = ex + lv[k];
                gbase[i] = bb + M[(size_t)j * nbuck + i];
                if (j == 0) bstart[i] = bb;
            }
        }
        if (j == 0 && t == 0) bstart[nbuck] = (unsigned)E;
    }
    __syncthreads();
    // 4. placement into stage (LDS random write, cheap)
    if (s < e) {
        int nq = (e - s) >> 2;
        const int4* r4 = (const int4*)(row + s);
        const int4* c4 = (const int4*)(col + s);
        for (int q = t; q < nq; q += blockDim.x) {
            int4 r = r4[q];
            int4 c = c4[q];
            unsigned p0 = atomicAdd(&lcur[((unsigned)c.x) >> SHIFT], 1u);
            unsigned p1 = atomicAdd(&lcur[((unsigned)c.y) >> SHIFT], 1u);
            unsigned p2 = atomicAdd(&lcur[((unsigned)c.z) >> SHIFT], 1u);
            unsigned p3 = atomicAdd(&lcur[((unsigned)c.w) >> SHIFT], 1u);
            stage[p0] = (unsigned)r.x | (((unsigned)c.x & (BSZ - 1)) << 17);
            stage[p1] = (unsigned)r.y | (((unsigned)c.y & (BSZ - 1)) << 17);
            stage[p2] = (unsigned)r.z | (((unsigned)c.z & (BSZ - 1)) << 17);
            stage[p3] = (unsigned)r.w | (((unsigned)c.w & (BSZ - 1)) << 17);
        }
        for (int k = s + (nq << 2) + t; k < e; k += blockDim.x) {
            unsigned c = (unsigned)col[k];
            unsigned pos = atomicAdd(&lcur[c >> SHIFT], 1u);
            stage[pos] = (unsigned)row[k] | ((c & (BSZ - 1)) << 17);
        }
    }
    __syncthreads();
    // 5. flush: per wave per bucket, consecutive lanes -> consecutive addresses
    int wid = t >> 6, lane = t & 63, nw = blockDim.x >> 6;
    for (int b = wid; b < nbuck; b += nw) {
        unsigned cntb = h[b], lo = lofs[b], go = gbase[b];
        for (unsigned i = lane; i < cntb; i += 64)
            out[go + i] = stage[lo + i];
    }
}

// ---- K4: degree count + node0 epilogue (dinv, g0 = dinv * x.u) ----
__global__ void degnode0_kernel(const unsigned* __restrict__ buck,
                                const unsigned* __restrict__ bstart,
                                const float* __restrict__ x, const float* __restrict__ coeff,
                                float* __restrict__ dinv, float* __restrict__ g, int n) {
    __shared__ float acc[BSZ];
    int b = blockIdx.x;
    if (threadIdx.x < BSZ) acc[threadIdx.x] = 0.f;
    __syncthreads();
    unsigned s = bstart[b], e = bstart[b + 1];
    unsigned sa = (s + 3u) & ~3u;
    if (sa > e) sa = e;
    if (s + threadIdx.x < sa)
        atomicAdd(&acc[buck[s + threadIdx.x] >> 17], 1.0f);
    unsigned nq = (e - sa) >> 2;
    const uint4* bq = (const uint4*)(buck + sa);
    for (unsigned q = threadIdx.x; q < nq; q += blockDim.x) {
        uint4 w = bq[q];
        atomicAdd(&acc[w.x >> 17], 1.0f);
        atomicAdd(&acc[w.y >> 17], 1.0f);
        atomicAdd(&acc[w.z >> 17], 1.0f);
        atomicAdd(&acc[w.w >> 17], 1.0f);
    }
    for (unsigned k = sa + (nq << 2) + threadIdx.x; k < e; k += blockDim.x)
        atomicAdd(&acc[buck[k] >> 17], 1.0f);
    __syncthreads();
    int node = b * BSZ + threadIdx.x;
    if (threadIdx.x < BSZ && node < n) {
        float d = rsqrtf(acc[threadIdx.x] + 1.0f);
        dinv[node] = d;
        float4 xv = ((const float4*)x)[node];
        float t0 = xv.x * coeff[0] + xv.y * coeff[1] + xv.z * coeff[2] + xv.w * coeff[3];
        g[node] = d * t0;
    }
}

// ---- K5/K6: gather pass with fused node epilogue ----
__global__ void gather_kernel(const unsigned* __restrict__ buck,
                              const unsigned* __restrict__ bstart,
                              const float* __restrict__ dinv, const float* __restrict__ gin,
                              float* __restrict__ gout, const float* __restrict__ coeff,
                              int sidx, int n) {
    __shared__ float acc[BSZ];
    int b = blockIdx.x;
    if (threadIdx.x < BSZ) acc[threadIdx.x] = 0.f;
    __syncthreads();
    unsigned s = bstart[b], e = bstart[b + 1];
    unsigned sa = (s + 3u) & ~3u;
    if (sa > e) sa = e;
    if (s + threadIdx.x < sa) {
        unsigned w = buck[s + threadIdx.x];
        atomicAdd(&acc[w >> 17], gin[w & ROWMASK]);
    }
    unsigned nq = (e - sa) >> 2;
    const uint4* bq = (const uint4*)(buck + sa);
    for (unsigned q = threadIdx.x; q < nq; q += blockDim.x) {
        uint4 w = bq[q];
        float a0 = gin[w.x & ROWMASK];
        float a1 = gin[w.y & ROWMASK];
        float a2 = gin[w.z & ROWMASK];
        float a3 = gin[w.w & ROWMASK];
        atomicAdd(&acc[w.x >> 17], a0);
        atomicAdd(&acc[w.y >> 17], a1);
        atomicAdd(&acc[w.z >> 17], a2);
        atomicAdd(&acc[w.w >> 17], a3);
    }
    for (unsigned k = sa + (nq << 2) + threadIdx.x; k < e; k += blockDim.x) {
        unsigned w = buck[k];
        atomicAdd(&acc[w >> 17], gin[w & ROWMASK]);
    }
    __syncthreads();
    int node = b * BSZ + threadIdx.x;
    if (threadIdx.x < BSZ && node < n) {
        float d = dinv[node];
        float t = d * (acc[threadIdx.x] + gin[node]) + coeff[sidx];
        gout[node] = d * t;
    }
}

// ---- K7: pass 3 gather + fused segmented mean-pool (batch sorted) ----
__global__ void gatherpool_kernel(const unsigned* __restrict__ buck,
                                  const unsigned* __restrict__ bstart,
                                  const float* __restrict__ dinv, const float* __restrict__ gin,
                                  const float* __restrict__ coeff, const int* __restrict__ batch,
                                  float* __restrict__ sums, float* __restrict__ cnt, int n) {
    __shared__ float acc[BSZ];
    __shared__ float ls[PSLOTS], lc[PSLOTS];
    __shared__ int bF;
    int b = blockIdx.x;
    if (threadIdx.x < BSZ) acc[threadIdx.x] = 0.f;
    for (int i = threadIdx.x; i < PSLOTS; i += blockDim.x) { ls[i] = 0.f; lc[i] = 0.f; }
    if (threadIdx.x == 0) bF = batch[min(b * BSZ, n - 1)];
    __syncthreads();
    unsigned s = bstart[b], e = bstart[b + 1];
    unsigned sa = (s + 3u) & ~3u;
    if (sa > e) sa = e;
    if (s + threadIdx.x < sa) {
        unsigned w = buck[s + threadIdx.x];
        atomicAdd(&acc[w >> 17], gin[w & ROWMASK]);
    }
    unsigned nq = (e - sa) >> 2;
    const uint4* bq = (const uint4*)(buck + sa);
    for (unsigned q = threadIdx.x; q < nq; q += blockDim.x) {
        uint4 w = bq[q];
        float a0 = gin[w.x & ROWMASK];
        float a1 = gin[w.y & ROWMASK];
        float a2 = gin[w.z & ROWMASK];
        float a3 = gin[w.w & ROWMASK];
        atomicAdd(&acc[w.x >> 17], a0);
        atomicAdd(&acc[w.y >> 17], a1);
        atomicAdd(&acc[w.z >> 17], a2);
        atomicAdd(&acc[w.w >> 17], a3);
    }
    for (unsigned k = sa + (nq << 2) + threadIdx.x; k < e; k += blockDim.x) {
        unsigned w = buck[k];
        atomicAdd(&acc[w >> 17], gin[w & ROWMASK]);
    }
    __syncthreads();
    int node = b * BSZ + threadIdx.x;
    if (threadIdx.x < BSZ && node < n) {
        float d = dinv[node];
        float t3 = d * (acc[threadIdx.x] + gin[node]) + coeff[6];
        int rb = batch[node] - bF;               // batch sorted -> rb >= 0
        if (rb < PSLOTS) {
            atomicAdd(&ls[rb], t3);
            atomicAdd(&lc[rb], 1.0f);
        } else {
            atomicAdd(&sums[bF + rb], t3);
            atomicAdd(&cnt[bF + rb], 1.0f);
        }
    }
    __syncthreads();
    for (int i = threadIdx.x; i < PSLOTS; i += blockDim.x) {
        if (lc[i] != 0.f) {
            atomicAdd(&sums[bF + i], ls[i]);
            atomicAdd(&cnt[bF + i], lc[i]);
        }
    }
}

// ---- K8: mean + linear bias + sigmoid ----
__global__ void final_kernel(const float* __restrict__ sums, const float* __restrict__ cnt,
                             const float* __restrict__ coeff, float* __restrict__ out,
                             int ngraphs) {
    int i = blockIdx.x * blockDim.x + threadIdx.x;
    if (i < ngraphs) {
        float m = sums[i] / fmaxf(cnt[i], 1.0f) + coeff[7];
        out[i] = 1.0f / (1.0f + expf(-m));
    }
}

// ======================= fallback (R1 atomic path) =========================
__global__ void fb_coeffs_kernel(const float* __restrict__ W1, const float* __restrict__ b1,
                                 const float* __restrict__ W2, const float* __restrict__ b2,
                                 const float* __restrict__ W3, const float* __restrict__ b3,
                                 const float* __restrict__ lin_w, const float* __restrict__ lin_b,
                                 float* __restrict__ coeff,
                                 float* __restrict__ sums, float* __restrict__ cnt, int ngraphs) {
    for (int i = threadIdx.x; i < ngraphs; i += blockDim.x) { sums[i] = 0.f; cnt[i] = 0.f; }
    if (threadIdx.x == 0) {
        float w3l[16], w2l[16];
        for (int i = 0; i < 16; ++i) {
            float s = 0.f;
            for (int j = 0; j < 16; ++j) s += W3[i * 16 + j] * lin_w[j];
            w3l[i] = s;
        }
        for (int i = 0; i < 16; ++i) {
            float s = 0.f;
            for (int j = 0; j < 16; ++j) s += W2[i * 16 + j] * w3l[j];
            w2l[i] = s;
        }
        for (int i = 0; i < 4; ++i) {
            float s = 0.f;
            for (int j = 0; j < 16; ++j) s += W1[i * 16 + j] * w2l[j];
            coeff[i] = s;
        }
        float s2 = 0.f, s1 = 0.f, s0 = 0.f;
        for (int j = 0; j < 16; ++j) {
            s2 += b1[j] * w2l[j];
            s1 += b2[j] * w3l[j];
            s0 += b3[j] * lin_w[j];
        }
        coeff[4] = s2; coeff[5] = s1; coeff[6] = s0; coeff[7] = lin_b[0];
    }
}
__global__ void fb_init_kernel(float* __restrict__ deg, int n) {
    int i = blockIdx.x * blockDim.x + threadIdx.x;
    int stride = gridDim.x * blockDim.x;
    for (int k = i; k < n; k += stride) deg[k] = 1.0f;
}
__global__ void fb_deg_kernel(const int* __restrict__ col, float* __restrict__ deg, int E) {
    int i = blockIdx.x * blockDim.x + threadIdx.x;
    int stride = gridDim.x * blockDim.x;
    for (int k = i; k < E; k += stride) atomicAdd(&deg[col[k]], 1.0f);
}
__global__ void fb_node0_kernel(const float* __restrict__ x, const float* __restrict__ coeff,
                                float* __restrict__ deg_dinv, float* __restrict__ g,
                                float* __restrict__ acc, int n) {
    int i = blockIdx.x * blockDim.x + threadIdx.x;
    int stride = gridDim.x * blockDim.x;
    for (int k = i; k < n; k += stride) {
        float d = rsqrtf(deg_dinv[k]);
        deg_dinv[k] = d;
        float4 xv = ((const float4*)x)[k];
        float t0 = xv.x * coeff[0] + xv.y * coeff[1] + xv.z * coeff[2] + xv.w * coeff[3];
        g[k] = d * t0;
        acc[k] = 0.f;
    }
}
__global__ void fb_edge_kernel(const int* __restrict__ ei, const float* __restrict__ g,
                               float* __restrict__ acc, int E) {
    int i = blockIdx.x * blockDim.x + threadIdx.x;
    int stride = gridDim.x * blockDim.x;
    for (int k = i; k < E; k += stride) atomicAdd(&acc[ei[E + k]], g[ei[k]]);
}
__global__ void fb_node_kernel(const float* __restrict__ dinv, float* __restrict__ g,
                               float* __restrict__ acc, const float* __restrict__ coeff,
                               int sidx, int n) {
    int i = blockIdx.x * blockDim.x + threadIdx.x;
    int stride = gridDim.x * blockDim.x;
    for (int k = i; k < n; k += stride) {
        float d = dinv[k];
        float t = d * (acc[k] + g[k]) + coeff[sidx];
        g[k] = d * t;
        acc[k] = 0.f;
    }
}
__global__ void fb_pool_kernel(const float* __restrict__ dinv, const float* __restrict__ g,
                               const float* __restrict__ acc, const float* __restrict__ coeff,
                               const int* __restrict__ batch, float* __restrict__ sums,
                               float* __restrict__ cnt, int n) {
    int i = blockIdx.x * blockDim.x + threadIdx.x;
    int stride = gridDim.x * blockDim.x;
    for (int k = i; k < n; k += stride) {
        float d = dinv[k];
        float t3 = d * (acc[k] + g[k]) + coeff[6];
        int b = batch[k];
        atomicAdd(&sums[b], t3);
        atomicAdd(&cnt[b], 1.0f);
    }
}
// ===========================================================================

extern "C" void kernel_launch(void* const* d_in, const int* in_sizes, int n_in,
                              void* d_out, int out_size, void* d_ws, size_t ws_size,
                              hipStream_t stream) {
    const float* x     = (const float*)d_in[0];
    const int*   ei    = (const int*)d_in[1];
    const int*   batch = (const int*)d_in[2];
    const float* W1    = (const float*)d_in[3];
    const float* b1    = (const float*)d_in[4];
    const float* W2    = (const float*)d_in[5];
    const float* b2    = (const float*)d_in[6];
    const float* W3    = (const float*)d_in[7];
    const float* b3    = (const float*)d_in[8];
    const float* lin_w = (const float*)d_in[9];
    const float* lin_b = (const float*)d_in[10];

    const int n       = in_sizes[0] / 4;   // 100000
    const int E       = in_sizes[1] / 2;   // 3200000
    const int ngraphs = out_size;          // 1000

    const int nbuck = (n + BSZ - 1) / BSZ; // 391
    const int B = 256;

    size_t npad  = ((size_t)n + 255) & ~(size_t)255;
    size_t gpad  = ((size_t)ngraphs + 255) & ~(size_t)255;
    size_t nbpad = ((size_t)nbuck + 1 + 255) & ~(size_t)255;
    size_t mlen  = (size_t)NB_SCAT * nbuck;

    size_t need = (256 + mlen + 2 * nbpad + (size_t)E + 3 * npad + 2 * gpad) * 4;

    float* ws    = (float*)d_ws;
    float* coeff = ws;                                    // 256
    unsigned* M        = (unsigned*)(coeff + 256);        // mlen
    unsigned* binTotal = M + mlen;                        // nbpad
    unsigned* bstart   = binTotal + nbpad;                // nbpad
    unsigned* buck     = bstart + nbpad;                  // E (16B aligned)
    float* dinv  = (float*)(buck + E);                    // npad
    float* gA    = dinv + npad;                           // npad
    float* gB    = gA + npad;                             // npad
    float* sums  = gB + npad;                             // gpad
    float* cnt   = sums + gpad;                           // gpad

    int tile = (((E + NB_SCAT - 1) / NB_SCAT) + 3) & ~3;   // multiple of 4
    size_t ldsScat = (size_t)(4 * nbuck + B_SCAT + tile) * sizeof(unsigned);

    bool mainok = (n < (1 << 17)) && nbuck >= 1 && nbuck <= MAXNB &&
                  ws_size >= need && ldsScat <= 63 * 1024;

    if (!mainok) {
        // -------- fallback: R1 atomic path --------
        float* fcoeff = ws;
        float* deg = fcoeff + 256;
        float* g   = deg + npad;
        float* acc = g + npad;
        float* fsums = acc + npad;
        float* fcnt  = fsums + gpad;
        int nodeBlocks = (n + B - 1) / B;
        int edgeBlocks = (E + B - 1) / B;
        fb_coeffs_kernel<<<1, 64, 0, stream>>>(W1, b1, W2, b2, W3, b3, lin_w, lin_b, fcoeff,
                                               fsums, fcnt, ngraphs);
        fb_init_kernel<<<nodeBlocks, B, 0, stream>>>(deg, n);
        fb_deg_kernel<<<edgeBlocks, B, 0, stream>>>(ei + E, deg, E);
        fb_node0_kernel<<<nodeBlocks, B, 0, stream>>>(x, fcoeff, deg, g, acc, n);
        fb_edge_kernel<<<edgeBlocks, B, 0, stream>>>(ei, g, acc, E);
        fb_node_kernel<<<nodeBlocks, B, 0, stream>>>(deg, g, acc, fcoeff, 4, n);
        fb_edge_kernel<<<edgeBlocks, B, 0, stream>>>(ei, g, acc, E);
        fb_node_kernel<<<nodeBlocks, B, 0, stream>>>(deg, g, acc, fcoeff, 5, n);
        fb_edge_kernel<<<edgeBlocks, B, 0, stream>>>(ei, g, acc, E);
        fb_pool_kernel<<<nodeBlocks, B, 0, stream>>>(deg, g, acc, fcoeff, batch, fsums, fcnt, n);
        final_kernel<<<(ngraphs + B - 1) / B, B, 0, stream>>>(fsums, fcnt, fcoeff, (float*)d_out, ngraphs);
        return;
    }

    size_t ldsHist = (size_t)nbuck * sizeof(unsigned);

    hist_kernel<<<NB_SCAT, B_SCAT, ldsHist, stream>>>(ei + E, E, tile, nbuck, M,
                                                      W1, b1, W2, b2, W3, b3, lin_w, lin_b,
                                                      coeff, sums, cnt, ngraphs);
    scanA_kernel<<<nbuck, NB_SCAT, 0, stream>>>(M, binTotal, nbuck);
    scatter_kernel<<<NB_SCAT, B_SCAT, ldsScat, stream>>>(ei, ei + E, E, tile, nbuck, M,
                                                         binTotal, bstart, buck);

    degnode0_kernel<<<nbuck, B_GATH, 0, stream>>>(buck, bstart, x, coeff, dinv, gA, n);
    gather_kernel<<<nbuck, B_GATH, 0, stream>>>(buck, bstart, dinv, gA, gB, coeff, 4, n);
    gather_kernel<<<nbuck, B_GATH, 0, stream>>>(buck, bstart, dinv, gB, gA, coeff, 5, n);
    gatherpool_kernel<<<nbuck, B_GATH, 0, stream>>>(buck, bstart, dinv, gA, coeff, batch,
                                                    sums, cnt, n);

    final_kernel<<<(ngraphs + B - 1) / B, B, 0, stream>>>(sums, cnt, coeff, (float*)d_out, ngraphs);
}

// Round 9
// 129.404 us; speedup vs baseline: 1.1588x; 1.1330x over previous
//
#include <hip/hip_runtime.h>
#include <math.h>

// ---------------------------------------------------------------------------
// GCN: 3x GCNConv (linear) -> mean pool -> linear -> sigmoid.
// Linear-collapse identity (absmax 0.0 through R8):
//   h3 @ lin_w = A(A(A(X u) + s2) + s1) + s0,  u = W1W2W3 lin_w.
// R8 lesson: WRITE-amp and transaction issues fixed; remaining ~130us is
// spread across kernels that all run at 1-4 waves/SIMD (scatter: 1 block/CU
// with 54KB LDS = 1 wave/SIMD streaming 25.6MB). R9: 1024-thread blocks for
// hist/scatter and all bucket kernels -> 16-24 waves/CU; same algorithm.
// ---------------------------------------------------------------------------

#define SHIFT      8
#define BSZ        256         // nodes per bucket = 1<<SHIFT
#define NB_SCAT    256         // blocks for hist/scatter phases
#define B_SCAT     1024        // threads for hist/scatter
#define B_GATH     1024        // threads for bucket (gather) kernels
#define ROWMASK    0x1FFFFu    // 17 bits for row id (n < 131072)
#define PSLOTS     64          // LDS pool slots per pass-3 block
#define MAXNB      2048        // nbuck guard (scan chunking)

// ---- K1: histogram of col>>SHIFT (M[j][bin]) + coeffs + sums/cnt zero ----
__global__ void hist_kernel(const int* __restrict__ col, int E, int tile, int nbuck,
                            unsigned* __restrict__ M,
                            const float* __restrict__ W1, const float* __restrict__ b1,
                            const float* __restrict__ W2, const float* __restrict__ b2,
                            const float* __restrict__ W3, const float* __restrict__ b3,
                            const float* __restrict__ lin_w, const float* __restrict__ lin_b,
                            float* __restrict__ coeff,
                            float* __restrict__ sums, float* __restrict__ cnt, int ngraphs) {
    extern __shared__ unsigned h[];
    __shared__ float w3l[16], w2l[16];
    int t = threadIdx.x;
    for (int i = t; i < nbuck; i += blockDim.x) h[i] = 0;
    if (blockIdx.x == 0) {
        for (int i = t; i < ngraphs; i += blockDim.x) { sums[i] = 0.f; cnt[i] = 0.f; }
        if (t < 16) {
            float s = 0.f;
            for (int j = 0; j < 16; ++j) s += W3[t * 16 + j] * lin_w[j];
            w3l[t] = s;
        }
    }
    __syncthreads();
    if (blockIdx.x == 0 && t < 16) {
        float s = 0.f;
        for (int j = 0; j < 16; ++j) s += W2[t * 16 + j] * w3l[j];
        w2l[t] = s;
    }
    __syncthreads();
    if (blockIdx.x == 0) {
        if (t < 4) {
            float s = 0.f;
            for (int j = 0; j < 16; ++j) s += W1[t * 16 + j] * w2l[j];
            coeff[t] = s;
        } else if (t == 4) {
            float s = 0.f;
            for (int j = 0; j < 16; ++j) s += b1[j] * w2l[j];
            coeff[4] = s;
        } else if (t == 5) {
            float s = 0.f;
            for (int j = 0; j < 16; ++j) s += b2[j] * w3l[j];
            coeff[5] = s;
        } else if (t == 6) {
            float s = 0.f;
            for (int j = 0; j < 16; ++j) s += b3[j] * lin_w[j];
            coeff[6] = s;
        } else if (t == 7) {
            coeff[7] = lin_b[0];
        }
    }
    // histogram
    int b = blockIdx.x;
    int s = b * tile, e = min(s + tile, E);          // s multiple of 4
    if (s < e) {
        int nq = (e - s) >> 2;
        const int4* c4 = (const int4*)(col + s);
        for (int q = t; q < nq; q += blockDim.x) {
            int4 c = c4[q];
            atomicAdd(&h[((unsigned)c.x) >> SHIFT], 1u);
            atomicAdd(&h[((unsigned)c.y) >> SHIFT], 1u);
            atomicAdd(&h[((unsigned)c.z) >> SHIFT], 1u);
            atomicAdd(&h[((unsigned)c.w) >> SHIFT], 1u);
        }
        for (int k = s + (nq << 2) + t; k < e; k += blockDim.x)
            atomicAdd(&h[((unsigned)col[k]) >> SHIFT], 1u);
    }
    __syncthreads();
    for (int i = t; i < nbuck; i += blockDim.x)
        M[(size_t)b * nbuck + i] = h[i];
}

// ---- K2: per-bin exclusive scan over the NB_SCAT block counts ----
__global__ void scanA_kernel(unsigned* __restrict__ M, unsigned* __restrict__ binTotal,
                             int nbuck) {
    __shared__ unsigned sc[NB_SCAT];
    int b = blockIdx.x;
    int t = threadIdx.x;
    unsigned v = M[(size_t)t * nbuck + b];
    sc[t] = v;
    __syncthreads();
    for (int off = 1; off < NB_SCAT; off <<= 1) {
        unsigned u = (t >= off) ? sc[t - off] : 0u;
        __syncthreads();
        sc[t] += u;
        __syncthreads();
    }
    M[(size_t)t * nbuck + b] = sc[t] - v;     // exclusive within bin
    if (t == NB_SCAT - 1) binTotal[b] = sc[t];
}

// ---- K3: scatter via block-local LDS counting sort; coalesced flush ----
// pack: row(17b) | col_low(8b)<<17
__global__ void scatter_kernel(const int* __restrict__ row, const int* __restrict__ col,
                               int E, int tile, int nbuck,
                               const unsigned* __restrict__ M,
                               const unsigned* __restrict__ binTotal,
                               unsigned* __restrict__ bstart,
                               unsigned* __restrict__ out) {
    extern __shared__ unsigned lds[];
    unsigned* h     = lds;                   // nbuck  local counts
    unsigned* lofs  = lds + nbuck;           // nbuck  local exclusive offsets
    unsigned* lcur  = lds + 2 * nbuck;       // nbuck  placement cursors
    unsigned* gbase = lds + 3 * nbuck;       // nbuck  global run starts (this block)
    unsigned* tsum  = lds + 4 * nbuck;       // B_SCAT scan workspace
    unsigned* stage = lds + 4 * nbuck + B_SCAT; // tile  staged packed words
    int t = threadIdx.x, j = blockIdx.x;
    for (int i = t; i < nbuck; i += blockDim.x) h[i] = 0;
    __syncthreads();
    int s = j * tile, e = min(s + tile, E);
    // 1. local hist
    if (s < e) {
        int nq = (e - s) >> 2;
        const int4* c4 = (const int4*)(col + s);
        for (int q = t; q < nq; q += blockDim.x) {
            int4 c = c4[q];
            atomicAdd(&h[((unsigned)c.x) >> SHIFT], 1u);
            atomicAdd(&h[((unsigned)c.y) >> SHIFT], 1u);
            atomicAdd(&h[((unsigned)c.z) >> SHIFT], 1u);
            atomicAdd(&h[((unsigned)c.w) >> SHIFT], 1u);
        }
        for (int k = s + (nq << 2) + t; k < e; k += blockDim.x)
            atomicAdd(&h[((unsigned)col[k]) >> SHIFT], 1u);
    }
    __syncthreads();
    const int C = MAXNB / B_SCAT;            // 2 elems/thread
    unsigned lv[C];
    // 2. scan h -> lofs/lcur (exclusive)
    {
        unsigned run = 0;
        for (int k = 0; k < C; ++k) {
            int i = t * C + k;
            unsigned x = (i < nbuck) ? h[i] : 0u;
            lv[k] = run; run += x;
        }
        tsum[t] = run;
        __syncthreads();
        for (int off = 1; off < B_SCAT; off <<= 1) {
            unsigned u = (t >= off) ? tsum[t - off] : 0u;
            __syncthreads();
            tsum[t] += u;
            __syncthreads();
        }
        unsigned ex = (t == 0) ? 0u : tsum[t - 1];
        for (int k = 0; k < C; ++k) {
            int i = t * C + k;
            if (i < nbuck) { lofs[i] = ex + lv[k]; lcur[i] = ex + lv[k]; }
        }
    }
    __syncthreads();
    // 3. gbase[i] = (exclusive scan of binTotal)[i] + M[j][i]; block 0 stores bstart
    {
        unsigned run = 0;
        for (int k = 0; k < C; ++k) {
            int i = t * C + k;
            unsigned x = (i < nbuck) ? binTotal[i] : 0u;
            lv[k] = run; run += x;
        }
        tsum[t] = run;
        __syncthreads();
        for (int off = 1; off < B_SCAT; off <<= 1) {
            unsigned u = (t >= off) ? tsum[t - off] : 0u;
            __syncthreads();
            tsum[t] += u;
            __syncthreads();
        }
        unsigned ex = (t == 0) ? 0u : tsum[t - 1];
        for (int k = 0; k < C; ++k) {
            int i = t * C + k;
            if (i < nbuck) {
                unsigned bb = ex + lv[k];
                gbase[i] = bb + M[(size_t)j * nbuck + i];
                if (j == 0) bstart[i] = bb;
            }
        }
        if (j == 0 && t == 0) bstart[nbuck] = (unsigned)E;
    }
    __syncthreads();
    // 4. placement into stage (LDS random write, cheap)
    if (s < e) {
        int nq = (e - s) >> 2;
        const int4* r4 = (const int4*)(row + s);
        const int4* c4 = (const int4*)(col + s);
        for (int q = t; q < nq; q += blockDim.x) {
            int4 r = r4[q];
            int4 c = c4[q];
            unsigned p0 = atomicAdd(&lcur[((unsigned)c.x) >> SHIFT], 1u);
            unsigned p1 = atomicAdd(&lcur[((unsigned)c.y) >> SHIFT], 1u);
            unsigned p2 = atomicAdd(&lcur[((unsigned)c.z) >> SHIFT], 1u);
            unsigned p3 = atomicAdd(&lcur[((unsigned)c.w) >> SHIFT], 1u);
            stage[p0] = (unsigned)r.x | (((unsigned)c.x & (BSZ - 1)) << 17);
            stage[p1] = (unsigned)r.y | (((unsigned)c.y & (BSZ - 1)) << 17);
            stage[p2] = (unsigned)r.z | (((unsigned)c.z & (BSZ - 1)) << 17);
            stage[p3] = (unsigned)r.w | (((unsigned)c.w & (BSZ - 1)) << 17);
        }
        for (int k = s + (nq << 2) + t; k < e; k += blockDim.x) {
            unsigned c = (unsigned)col[k];
            unsigned pos = atomicAdd(&lcur[c >> SHIFT], 1u);
            stage[pos] = (unsigned)row[k] | ((c & (BSZ - 1)) << 17);
        }
    }
    __syncthreads();
    // 5. flush: per wave per bucket, consecutive lanes -> consecutive addresses
    int wid = t >> 6, lane = t & 63, nw = blockDim.x >> 6;
    for (int b = wid; b < nbuck; b += nw) {
        unsigned cntb = h[b], lo = lofs[b], go = gbase[b];
        for (unsigned i = lane; i < cntb; i += 64)
            out[go + i] = stage[lo + i];
    }
}

// ---- K4: degree count + node0 epilogue (dinv, g0 = dinv * x.u) ----
__global__ void degnode0_kernel(const unsigned* __restrict__ buck,
                                const unsigned* __restrict__ bstart,
                                const float* __restrict__ x, const float* __restrict__ coeff,
                                float* __restrict__ dinv, float* __restrict__ g, int n) {
    __shared__ float acc[BSZ];
    int b = blockIdx.x;
    if (threadIdx.x < BSZ) acc[threadIdx.x] = 0.f;
    __syncthreads();
    unsigned s = bstart[b], e = bstart[b + 1];
    unsigned sa = (s + 3u) & ~3u;
    if (sa > e) sa = e;
    if (s + threadIdx.x < sa)
        atomicAdd(&acc[buck[s + threadIdx.x] >> 17], 1.0f);
    unsigned nq = (e - sa) >> 2;
    const uint4* bq = (const uint4*)(buck + sa);
    for (unsigned q = threadIdx.x; q < nq; q += blockDim.x) {
        uint4 w = bq[q];
        atomicAdd(&acc[w.x >> 17], 1.0f);
        atomicAdd(&acc[w.y >> 17], 1.0f);
        atomicAdd(&acc[w.z >> 17], 1.0f);
        atomicAdd(&acc[w.w >> 17], 1.0f);
    }
    for (unsigned k = sa + (nq << 2) + threadIdx.x; k < e; k += blockDim.x)
        atomicAdd(&acc[buck[k] >> 17], 1.0f);
    __syncthreads();
    int node = b * BSZ + threadIdx.x;
    if (threadIdx.x < BSZ && node < n) {
        float d = rsqrtf(acc[threadIdx.x] + 1.0f);
        dinv[node] = d;
        float4 xv = ((const float4*)x)[node];
        float t0 = xv.x * coeff[0] + xv.y * coeff[1] + xv.z * coeff[2] + xv.w * coeff[3];
        g[node] = d * t0;
    }
}

// ---- K5/K6: gather pass with fused node epilogue ----
__global__ void gather_kernel(const unsigned* __restrict__ buck,
                              const unsigned* __restrict__ bstart,
                              const float* __restrict__ dinv, const float* __restrict__ gin,
                              float* __restrict__ gout, const float* __restrict__ coeff,
                              int sidx, int n) {
    __shared__ float acc[BSZ];
    int b = blockIdx.x;
    if (threadIdx.x < BSZ) acc[threadIdx.x] = 0.f;
    __syncthreads();
    unsigned s = bstart[b], e = bstart[b + 1];
    unsigned sa = (s + 3u) & ~3u;
    if (sa > e) sa = e;
    if (s + threadIdx.x < sa) {
        unsigned w = buck[s + threadIdx.x];
        atomicAdd(&acc[w >> 17], gin[w & ROWMASK]);
    }
    unsigned nq = (e - sa) >> 2;
    const uint4* bq = (const uint4*)(buck + sa);
    for (unsigned q = threadIdx.x; q < nq; q += blockDim.x) {
        uint4 w = bq[q];
        float a0 = gin[w.x & ROWMASK];
        float a1 = gin[w.y & ROWMASK];
        float a2 = gin[w.z & ROWMASK];
        float a3 = gin[w.w & ROWMASK];
        atomicAdd(&acc[w.x >> 17], a0);
        atomicAdd(&acc[w.y >> 17], a1);
        atomicAdd(&acc[w.z >> 17], a2);
        atomicAdd(&acc[w.w >> 17], a3);
    }
    for (unsigned k = sa + (nq << 2) + threadIdx.x; k < e; k += blockDim.x) {
        unsigned w = buck[k];
        atomicAdd(&acc[w >> 17], gin[w & ROWMASK]);
    }
    __syncthreads();
    int node = b * BSZ + threadIdx.x;
    if (threadIdx.x < BSZ && node < n) {
        float d = dinv[node];
        float t = d * (acc[threadIdx.x] + gin[node]) + coeff[sidx];
        gout[node] = d * t;
    }
}

// ---- K7: pass 3 gather + fused segmented mean-pool (batch sorted) ----
__global__ void gatherpool_kernel(const unsigned* __restrict__ buck,
                                  const unsigned* __restrict__ bstart,
                                  const float* __restrict__ dinv, const float* __restrict__ gin,
                                  const float* __restrict__ coeff, const int* __restrict__ batch,
                                  float* __restrict__ sums, float* __restrict__ cnt, int n) {
    __shared__ float acc[BSZ];
    __shared__ float ls[PSLOTS], lc[PSLOTS];
    __shared__ int bF;
    int b = blockIdx.x;
    if (threadIdx.x < BSZ) acc[threadIdx.x] = 0.f;
    for (int i = threadIdx.x; i < PSLOTS; i += blockDim.x) { ls[i] = 0.f; lc[i] = 0.f; }
    if (threadIdx.x == 0) bF = batch[min(b * BSZ, n - 1)];
    __syncthreads();
    unsigned s = bstart[b], e = bstart[b + 1];
    unsigned sa = (s + 3u) & ~3u;
    if (sa > e) sa = e;
    if (s + threadIdx.x < sa) {
        unsigned w = buck[s + threadIdx.x];
        atomicAdd(&acc[w >> 17], gin[w & ROWMASK]);
    }
    unsigned nq = (e - sa) >> 2;
    const uint4* bq = (const uint4*)(buck + sa);
    for (unsigned q = threadIdx.x; q < nq; q += blockDim.x) {
        uint4 w = bq[q];
        float a0 = gin[w.x & ROWMASK];
        float a1 = gin[w.y & ROWMASK];
        float a2 = gin[w.z & ROWMASK];
        float a3 = gin[w.w & ROWMASK];
        atomicAdd(&acc[w.x >> 17], a0);
        atomicAdd(&acc[w.y >> 17], a1);
        atomicAdd(&acc[w.z >> 17], a2);
        atomicAdd(&acc[w.w >> 17], a3);
    }
    for (unsigned k = sa + (nq << 2) + threadIdx.x; k < e; k += blockDim.x) {
        unsigned w = buck[k];
        atomicAdd(&acc[w >> 17], gin[w & ROWMASK]);
    }
    __syncthreads();
    int node = b * BSZ + threadIdx.x;
    if (threadIdx.x < BSZ && node < n) {
        float d = dinv[node];
        float t3 = d * (acc[threadIdx.x] + gin[node]) + coeff[6];
        int rb = batch[node] - bF;               // batch sorted -> rb >= 0
        if (rb < PSLOTS) {
            atomicAdd(&ls[rb], t3);
            atomicAdd(&lc[rb], 1.0f);
        } else {
            atomicAdd(&sums[bF + rb], t3);
            atomicAdd(&cnt[bF + rb], 1.0f);
        }
    }
    __syncthreads();
    for (int i = threadIdx.x; i < PSLOTS; i += blockDim.x) {
        if (lc[i] != 0.f) {
            atomicAdd(&sums[bF + i], ls[i]);
            atomicAdd(&cnt[bF + i], lc[i]);
        }
    }
}

// ---- K8: mean + linear bias + sigmoid ----
__global__ void final_kernel(const float* __restrict__ sums, const float* __restrict__ cnt,
                             const float* __restrict__ coeff, float* __restrict__ out,
                             int ngraphs) {
    int i = blockIdx.x * blockDim.x + threadIdx.x;
    if (i < ngraphs) {
        float m = sums[i] / fmaxf(cnt[i], 1.0f) + coeff[7];
        out[i] = 1.0f / (1.0f + expf(-m));
    }
}

// ======================= fallback (R1 atomic path) =========================
__global__ void fb_coeffs_kernel(const float* __restrict__ W1, const float* __restrict__ b1,
                                 const float* __restrict__ W2, const float* __restrict__ b2,
                                 const float* __restrict__ W3, const float* __restrict__ b3,
                                 const float* __restrict__ lin_w, const float* __restrict__ lin_b,
                                 float* __restrict__ coeff,
                                 float* __restrict__ sums, float* __restrict__ cnt, int ngraphs) {
    for (int i = threadIdx.x; i < ngraphs; i += blockDim.x) { sums[i] = 0.f; cnt[i] = 0.f; }
    if (threadIdx.x == 0) {
        float w3l[16], w2l[16];
        for (int i = 0; i < 16; ++i) {
            float s = 0.f;
            for (int j = 0; j < 16; ++j) s += W3[i * 16 + j] * lin_w[j];
            w3l[i] = s;
        }
        for (int i = 0; i < 16; ++i) {
            float s = 0.f;
            for (int j = 0; j < 16; ++j) s += W2[i * 16 + j] * w3l[j];
            w2l[i] = s;
        }
        for (int i = 0; i < 4; ++i) {
            float s = 0.f;
            for (int j = 0; j < 16; ++j) s += W1[i * 16 + j] * w2l[j];
            coeff[i] = s;
        }
        float s2 = 0.f, s1 = 0.f, s0 = 0.f;
        for (int j = 0; j < 16; ++j) {
            s2 += b1[j] * w2l[j];
            s1 += b2[j] * w3l[j];
            s0 += b3[j] * lin_w[j];
        }
        coeff[4] = s2; coeff[5] = s1; coeff[6] = s0; coeff[7] = lin_b[0];
    }
}
__global__ void fb_init_kernel(float* __restrict__ deg, int n) {
    int i = blockIdx.x * blockDim.x + threadIdx.x;
    int stride = gridDim.x * blockDim.x;
    for (int k = i; k < n; k += stride) deg[k] = 1.0f;
}
__global__ void fb_deg_kernel(const int* __restrict__ col, float* __restrict__ deg, int E) {
    int i = blockIdx.x * blockDim.x + threadIdx.x;
    int stride = gridDim.x * blockDim.x;
    for (int k = i; k < E; k += stride) atomicAdd(&deg[col[k]], 1.0f);
}
__global__ void fb_node0_kernel(const float* __restrict__ x, const float* __restrict__ coeff,
                                float* __restrict__ deg_dinv, float* __restrict__ g,
                                float* __restrict__ acc, int n) {
    int i = blockIdx.x * blockDim.x + threadIdx.x;
    int stride = gridDim.x * blockDim.x;
    for (int k = i; k < n; k += stride) {
        float d = rsqrtf(deg_dinv[k]);
        deg_dinv[k] = d;
        float4 xv = ((const float4*)x)[k];
        float t0 = xv.x * coeff[0] + xv.y * coeff[1] + xv.z * coeff[2] + xv.w * coeff[3];
        g[k] = d * t0;
        acc[k] = 0.f;
    }
}
__global__ void fb_edge_kernel(const int* __restrict__ ei, const float* __restrict__ g,
                               float* __restrict__ acc, int E) {
    int i = blockIdx.x * blockDim.x + threadIdx.x;
    int stride = gridDim.x * blockDim.x;
    for (int k = i; k < E; k += stride) atomicAdd(&acc[ei[E + k]], g[ei[k]]);
}
__global__ void fb_node_kernel(const float* __restrict__ dinv, float* __restrict__ g,
                               float* __restrict__ acc, const float* __restrict__ coeff,
                               int sidx, int n) {
    int i = blockIdx.x * blockDim.x + threadIdx.x;
    int stride = gridDim.x * blockDim.x;
    for (int k = i; k < n; k += stride) {
        float d = dinv[k];
        float t = d * (acc[k] + g[k]) + coeff[sidx];
        g[k] = d * t;
        acc[k] = 0.f;
    }
}
__global__ void fb_pool_kernel(const float* __restrict__ dinv, const float* __restrict__ g,
                               const float* __restrict__ acc, const float* __restrict__ coeff,
                               const int* __restrict__ batch, float* __restrict__ sums,
                               float* __restrict__ cnt, int n) {
    int i = blockIdx.x * blockDim.x + threadIdx.x;
    int stride = gridDim.x * blockDim.x;
    for (int k = i; k < n; k += stride) {
        float d = dinv[k];
        float t3 = d * (acc[k] + g[k]) + coeff[6];
        int b = batch[k];
        atomicAdd(&sums[b], t3);
        atomicAdd(&cnt[b], 1.0f);
    }
}
// ===========================================================================

extern "C" void kernel_launch(void* const* d_in, const int* in_sizes, int n_in,
                              void* d_out, int out_size, void* d_ws, size_t ws_size,
                              hipStream_t stream) {
    const float* x     = (const float*)d_in[0];
    const int*   ei    = (const int*)d_in[1];
    const int*   batch = (const int*)d_in[2];
    const float* W1    = (const float*)d_in[3];
    const float* b1    = (const float*)d_in[4];
    const float* W2    = (const float*)d_in[5];
    const float* b2    = (const float*)d_in[6];
    const float* W3    = (const float*)d_in[7];
    const float* b3    = (const float*)d_in[8];
    const float* lin_w = (const float*)d_in[9];
    const float* lin_b = (const float*)d_in[10];

    const int n       = in_sizes[0] / 4;   // 100000
    const int E       = in_sizes[1] / 2;   // 3200000
    const int ngraphs = out_size;          // 1000

    const int nbuck = (n + BSZ - 1) / BSZ; // 391
    const int B = 256;

    size_t npad  = ((size_t)n + 255) & ~(size_t)255;
    size_t gpad  = ((size_t)ngraphs + 255) & ~(size_t)255;
    size_t nbpad = ((size_t)nbuck + 1 + 255) & ~(size_t)255;
    size_t mlen  = (size_t)NB_SCAT * nbuck;

    size_t need = (256 + mlen + 2 * nbpad + (size_t)E + 3 * npad + 2 * gpad) * 4;

    float* ws    = (float*)d_ws;
    float* coeff = ws;                                    // 256
    unsigned* M        = (unsigned*)(coeff + 256);        // mlen
    unsigned* binTotal = M + mlen;                        // nbpad
    unsigned* bstart   = binTotal + nbpad;                // nbpad
    unsigned* buck     = bstart + nbpad;                  // E (16B aligned)
    float* dinv  = (float*)(buck + E);                    // npad
    float* gA    = dinv + npad;                           // npad
    float* gB    = gA + npad;                             // npad
    float* sums  = gB + npad;                             // gpad
    float* cnt   = sums + gpad;                           // gpad

    int tile = (((E + NB_SCAT - 1) / NB_SCAT) + 3) & ~3;   // multiple of 4
    size_t ldsScat = (size_t)(4 * nbuck + B_SCAT + tile) * sizeof(unsigned);

    bool mainok = (n < (1 << 17)) && nbuck >= 1 && nbuck <= MAXNB &&
                  ws_size >= need && ldsScat <= 63 * 1024;

    if (!mainok) {
        // -------- fallback: R1 atomic path --------
        float* fcoeff = ws;
        float* deg = fcoeff + 256;
        float* g   = deg + npad;
        float* acc = g + npad;
        float* fsums = acc + npad;
        float* fcnt  = fsums + gpad;
        int nodeBlocks = (n + B - 1) / B;
        int edgeBlocks = (E + B - 1) / B;
        fb_coeffs_kernel<<<1, 64, 0, stream>>>(W1, b1, W2, b2, W3, b3, lin_w, lin_b, fcoeff,
                                               fsums, fcnt, ngraphs);
        fb_init_kernel<<<nodeBlocks, B, 0, stream>>>(deg, n);
        fb_deg_kernel<<<edgeBlocks, B, 0, stream>>>(ei + E, deg, E);
        fb_node0_kernel<<<nodeBlocks, B, 0, stream>>>(x, fcoeff, deg, g, acc, n);
        fb_edge_kernel<<<edgeBlocks, B, 0, stream>>>(ei, g, acc, E);
        fb_node_kernel<<<nodeBlocks, B, 0, stream>>>(deg, g, acc, fcoeff, 4, n);
        fb_edge_kernel<<<edgeBlocks, B, 0, stream>>>(ei, g, acc, E);
        fb_node_kernel<<<nodeBlocks, B, 0, stream>>>(deg, g, acc, fcoeff, 5, n);
        fb_edge_kernel<<<edgeBlocks, B, 0, stream>>>(ei, g, acc, E);
        fb_pool_kernel<<<nodeBlocks, B, 0, stream>>>(deg, g, acc, fcoeff, batch, fsums, fcnt, n);
        final_kernel<<<(ngraphs + B - 1) / B, B, 0, stream>>>(fsums, fcnt, fcoeff, (float*)d_out, ngraphs);
        return;
    }

    size_t ldsHist = (size_t)nbuck * sizeof(unsigned);

    hist_kernel<<<NB_SCAT, B_SCAT, ldsHist, stream>>>(ei + E, E, tile, nbuck, M,
                                                      W1, b1, W2, b2, W3, b3, lin_w, lin_b,
                                                      coeff, sums, cnt, ngraphs);
    scanA_kernel<<<nbuck, NB_SCAT, 0, stream>>>(M, binTotal, nbuck);
    scatter_kernel<<<NB_SCAT, B_SCAT, ldsScat, stream>>>(ei, ei + E, E, tile, nbuck, M,
                                                         binTotal, bstart, buck);

    degnode0_kernel<<<nbuck, B_GATH, 0, stream>>>(buck, bstart, x, coeff, dinv, gA, n);
    gather_kernel<<<nbuck, B_GATH, 0, stream>>>(buck, bstart, dinv, gA, gB, coeff, 4, n);
    gather_kernel<<<nbuck, B_GATH, 0, stream>>>(buck, bstart, dinv, gB, gA, coeff, 5, n);
    gatherpool_kernel<<<nbuck, B_GATH, 0, stream>>>(buck, bstart, dinv, gA, coeff, batch,
                                                    sums, cnt, n);

    final_kernel<<<(ngraphs + B - 1) / B, B, 0, stream>>>(sums, cnt, coeff, (float*)d_out, ngraphs);
}